// Round 3
// baseline (489.408 us; speedup 1.0000x reference)
//
#include <hip/hip_runtime.h>

// Problem constants (match reference)
#define NO    20000
#define KC    11
#define DIM   256
#define NT    100000
#define OUT_F 128
#define KSEL  10

#define WAVES_PER_BLOCK 4
#define NBLOCKS (NO / WAVES_PER_BLOCK)   // 5000
#define GS_BLOCKS (NT / WAVES_PER_BLOCK) // 25000

// ---------------------------------------------------------------------------
// Kernel 1: w2[d] = sum_f W[d,f] * A[OUT_F + f],  d in [0, 2*DIM)
// ---------------------------------------------------------------------------
__global__ void compute_w2_kernel(const float* __restrict__ W,
                                  const float* __restrict__ A,
                                  float* __restrict__ w2) {
    int d = blockIdx.x * blockDim.x + threadIdx.x;
    if (d < 2 * DIM) {
        const float* wrow = W + (size_t)d * OUT_F;
        double a0 = 0.0, a1 = 0.0, a2 = 0.0, a3 = 0.0;
#pragma unroll 8
        for (int f = 0; f < OUT_F; f += 4) {
            a0 += (double)wrow[f + 0] * (double)A[OUT_F + f + 0];
            a1 += (double)wrow[f + 1] * (double)A[OUT_F + f + 1];
            a2 += (double)wrow[f + 2] * (double)A[OUT_F + f + 2];
            a3 += (double)wrow[f + 3] * (double)A[OUT_F + f + 3];
        }
        w2[d] = (float)((a0 + a1) + (a2 + a3));
    }
}

// ---------------------------------------------------------------------------
// Kernel 1b: per-training-row scalars (unchanged from R2 — feeds b_out, so
// the butterfly order of s must stay identical).
//   g[t] = dot(dtrain[t], w2[256:512])   (f64)
//   s[t] = sum(dtrain[t])                (f32)
// ---------------------------------------------------------------------------
__global__ __launch_bounds__(WAVES_PER_BLOCK * 64)
void precompute_gs_kernel(const float* __restrict__ dtrain,
                          const float* __restrict__ w2,
                          double* __restrict__ gtab,
                          float*  __restrict__ stab) {
    const int lane = threadIdx.x & 63;
    const int wv   = threadIdx.x >> 6;
    const int t    = blockIdx.x * WAVES_PER_BLOCK + wv;   // grid covers NT exactly

    const float4 w2b = *(const float4*)(w2 + 256 + lane * 4);
    const float4 m   = *(const float4*)(dtrain + (size_t)t * DIM + lane * 4);

    double g = (double)m.x * w2b.x + (double)m.y * w2b.y
             + (double)m.z * w2b.z + (double)m.w * w2b.w;
    float  s = (m.x + m.y) + (m.z + m.w);

#pragma unroll
    for (int off = 32; off; off >>= 1) {
        g += __shfl_xor(g, off, 64);
        s += __shfl_xor(s, off, 64);
    }
    if (lane == 0) {
        gtab[t] = g;
        stab[t] = s;
    }
}

// ---------------------------------------------------------------------------
// Kernel 2: one wave per row n — low-VGPR streaming version.
//
// R2 post-mortem: holding c[11] + g/s/inds/ndr[11] arrays put the kernel at
// ~125-135 VGPRs against the 128 cap (spill + stuck at 4 waves/SIMD; est.
// ~110 us vs the ~79 us mixed-stream floor). This version targets <64 VGPRs
// -> 8 waves/SIMD (occupancy quantum doubles at the 64 boundary):
//   - candidate values are folded into e[k] on load and NOT held; the 10
//     surviving rows are re-loaded from L2/L3 at store time (rows in flight
//     per XCD ~2.8 MB ~ L2 size; no extra HBM traffic)
//   - metadata is lane-indexed: lane k owns neighbor k (6 regs, not 66);
//     uniform values are extracted with readlane-style __shfl
// Numeric orders feeding partA/partB are bitwise-identical to R2.
// ---------------------------------------------------------------------------
__global__ __launch_bounds__(WAVES_PER_BLOCK * 64, 8)
void select_kernel(const float* __restrict__ Cand,
                   const float* __restrict__ nd_in,
                   const int*   __restrict__ ni_in,
                   const double* __restrict__ gtab,
                   const float*  __restrict__ stab,
                   const float* __restrict__ w2,
                   float* __restrict__ outC,
                   float* __restrict__ outND,
                   float* __restrict__ outNI,
                   double* __restrict__ partA,
                   double* __restrict__ partB) {
    const int lane = threadIdx.x & 63;
    const int wv   = threadIdx.x >> 6;
    const int n    = blockIdx.x * WAVES_PER_BLOCK + wv;   // grid exactly covers NO

    const float4 w2a = *(const float4*)(w2 + lane * 4);

    // lane-parallel metadata: lane k (k < KC) owns neighbor k.
    int   idx0 = 0; float ndv = 0.f;
    if (lane < KC) {
        idx0 = ni_in[n * KC + lane];
        ndv  = nd_in[n * KC + lane];
    }
    double gl = 0.0; float sl = 0.f;
    if (lane < KC) {
        gl = gtab[idx0];           // 1.2 MB tables: L2-resident
        sl = stab[idx0];
    }

    // Streaming dot: candidate float4 consumed immediately, never held.
    const float* crow = Cand + ((size_t)n * KC) * DIM + lane * 4;
    double e[KC];
#pragma unroll
    for (int k = 0; k < KC; ++k) {
        const float4 c4 = *(const float4*)(crow + k * DIM);
        e[k] = (double)c4.x * w2a.x + (double)c4.y * w2a.y
             + (double)c4.z * w2a.z + (double)c4.w * w2a.w;
    }

    // stage-major butterfly (same order as R2): 11 chains overlap per stage
#pragma unroll
    for (int off = 32; off; off >>= 1) {
#pragma unroll
        for (int k = 0; k < KC; ++k)
            e[k] += __shfl_xor(e[k], off, 64);
    }

    // argmin scan with g-add (last tied index wins, as top_k drops it);
    // stot accumulated in the same k = 0..10 order as R2.
    double mine = 0.0;
    double stot = 0.0;
    int    drop = 0;
#pragma unroll
    for (int k = 0; k < KC; ++k) {
        const double gv = __shfl(gl, k, 64);   // readlane: uniform
        const float  sv = __shfl(sl, k, 64);
        const double et = e[k] + gv;
        if (k == 0 || et <= mine) { mine = et; drop = k; }
        stot += (double)sv;
    }
    const double sd = (double)__shfl(sl, drop, 64);   // drop is wave-uniform

    // Store the 10 surviving rows; values re-loaded from L2/L3 (rows were
    // fetched moments ago by this wave's own dot phase).
    const size_t ob = (size_t)n * KSEL * DIM + lane * 4;
#pragma unroll
    for (int j = 0; j < KSEL; ++j) {
        const int src = j + (j >= drop ? 1 : 0);
        const float4 v = *(const float4*)(crow + (size_t)src * DIM);
        *(float4*)(outC + ob + (size_t)j * DIM) = v;
    }

    // nd / ni epilogue via shuffle from the lane-held row (R1-verified).
    {
        const int srce = min(lane + (lane >= drop ? 1 : 0), KC - 1);
        const float ndo = __shfl(ndv, srce, 64);
        const int   nio = __shfl(idx0, srce, 64);
        if (lane < KSEL) {
            outND[n * KSEL + lane] = ndo;
            outNI[n * KSEL + lane] = (float)nio;   // exact for values < 2^24
        }
    }

    // Deterministic per-block partial sums for a_out / b_out (bitwise = R2)
    __shared__ double shA[WAVES_PER_BLOCK], shB[WAVES_PER_BLOCK];
    if (lane == 0) { shA[wv] = stot - sd; shB[wv] = sd; }
    __syncthreads();
    if (threadIdx.x == 0) {
        double a = 0.0, b = 0.0;
#pragma unroll
        for (int w = 0; w < WAVES_PER_BLOCK; ++w) { a += shA[w]; b += shB[w]; }
        partA[blockIdx.x] = a;
        partB[blockIdx.x] = b;
    }
}

// ---------------------------------------------------------------------------
// Kernel 3: reduce the 5000 block partials -> a_out, b_out (unchanged)
// ---------------------------------------------------------------------------
__global__ void finalize_kernel(const double* __restrict__ partA,
                                const double* __restrict__ partB,
                                float* __restrict__ outA,
                                float* __restrict__ outB) {
    __shared__ double sA[1024], sB[1024];
    double a = 0.0, b = 0.0;
    for (int i = threadIdx.x; i < NBLOCKS; i += 1024) {
        a += partA[i];
        b += partB[i];
    }
    sA[threadIdx.x] = a;
    sB[threadIdx.x] = b;
    __syncthreads();
    for (int s = 512; s; s >>= 1) {
        if (threadIdx.x < s) {
            sA[threadIdx.x] += sA[threadIdx.x + s];
            sB[threadIdx.x] += sB[threadIdx.x + s];
        }
        __syncthreads();
    }
    if (threadIdx.x == 0) {
        *outA = (float)(sA[0] / (double)((size_t)NO * KSEL));
        *outB = (float)(sB[0] / (double)NO);
    }
}

extern "C" void kernel_launch(void* const* d_in, const int* in_sizes, int n_in,
                              void* d_out, int out_size, void* d_ws, size_t ws_size,
                              hipStream_t stream) {
    // Input order: X, Candidate, neigh_dist, neigh_ind, data_m_train,
    //              data_m_batch, test, W, A
    const float* Cand   = (const float*)d_in[1];
    const float* ndist  = (const float*)d_in[2];
    const int*   nind   = (const int*)d_in[3];
    const float* dtrain = (const float*)d_in[4];
    const float* W      = (const float*)d_in[7];
    const float* A      = (const float*)d_in[8];

    float* out   = (float*)d_out;
    float* outC  = out;                                   // [NO, KSEL, DIM]
    float* outND = out + (size_t)NO * KSEL * DIM;         // [NO, KSEL]
    float* outNI = outND + (size_t)NO * KSEL;             // [NO, KSEL] (as f32)
    float* outA  = outNI + (size_t)NO * KSEL;             // scalar
    float* outB  = outA + 1;                              // scalar

    // Workspace layout:
    //   w2 (512 f32)                @ 0
    //   partA/partB (2 x 5000 f64)  @ 4096
    //   gtab (NT f64)               @ 128 KiB     (800 KB)
    //   stab (NT f32)               @ 128 KiB + 800 KB (400 KB)
    float*  w2    = (float*)d_ws;
    double* partA = (double*)((char*)d_ws + 4096);
    double* partB = partA + NBLOCKS;
    double* gtab  = (double*)((char*)d_ws + (1 << 17));
    float*  stab  = (float*)((char*)d_ws + (1 << 17) + (size_t)NT * sizeof(double));

    compute_w2_kernel<<<2, 256, 0, stream>>>(W, A, w2);
    precompute_gs_kernel<<<GS_BLOCKS, WAVES_PER_BLOCK * 64, 0, stream>>>(
        dtrain, w2, gtab, stab);
    select_kernel<<<NBLOCKS, WAVES_PER_BLOCK * 64, 0, stream>>>(
        Cand, ndist, nind, gtab, stab, w2, outC, outND, outNI, partA, partB);
    finalize_kernel<<<1, 1024, 0, stream>>>(partA, partB, outA, outB);
}